// Round 3
// baseline (230.062 us; speedup 1.0000x reference)
//
#include <hip/hip_runtime.h>

// Depthwise Conv1d: B=32, C=128, L=8192, K=3, pad=1, fp32.
// out[b,c,l] = w[c,0]*x[b,c,l-1] + w[c,1]*x[b,c,l] + w[c,2]*x[b,c,l+1] + bias[c]
// Memory-bound: ideal 128 MiB read + 128 MiB write → ~43 µs @ 6.3 TB/s.
//
// Wave-strided 2×float4 per thread: wave covers 128 contiguous float4 (512
// floats). Both loads are fully coalesced (64×16 B). All interior halos via
// shuffle; only lane0 (wave-left) and lane63 (wave-right) do a masked scalar
// load, zeroed at row edges. Channel is wave-uniform → weights via s_load.

constexpr int C  = 128;
constexpr int L  = 8192;
constexpr int L4 = L / 4;            // 2048 float4 per row
constexpr int B  = 32;
constexpr int TOTAL4 = B * C * L4;   // 8,388,608 float4
constexpr int NTHREADS = TOTAL4 / 2; // 4,194,304

__global__ __launch_bounds__(256) void dwconv1d_kernel(
    const float4* __restrict__ x4,
    const float* __restrict__ x,      // scalar view (edge halos)
    const float* __restrict__ w,      // [C,3]
    const float* __restrict__ bias,   // [C]
    float4* __restrict__ out4)
{
    int tid  = blockIdx.x * blockDim.x + threadIdx.x;
    int lane = threadIdx.x & 63;
    int wave = tid >> 6;

    int idx0 = wave * 128 + lane;      // first float4 chunk
    int idx1 = idx0 + 64;              // second float4 chunk (same row: 2048%128==0)

    // Channel is wave-uniform -> scalar loads for weights/bias.
    int c = __builtin_amdgcn_readfirstlane((idx0 >> 11) & (C - 1));
    float w0 = w[c * 3 + 0];
    float w1 = w[c * 3 + 1];
    float w2 = w[c * 3 + 2];
    float bc = bias[c];

    float4 v0 = x4[idx0];
    float4 v1 = x4[idx1];

    int i4_0 = idx0 & (L4 - 1);
    int i4_1 = idx1 & (L4 - 1);

    // Interior halos from neighbor lanes.
    float left0  = __shfl_up(v0.w, 1);
    float right0 = __shfl_down(v0.x, 1);
    float left1  = __shfl_up(v1.w, 1);
    float right1 = __shfl_down(v1.x, 1);

    // Chunk boundary inside the wave: lane63's right0 = lane0's v1.x,
    // lane0's left1 = lane63's v0.w.
    float bx = __shfl(v1.x, 0);
    float lx = __shfl(v0.w, 63);
    if (lane == 63) right0 = bx;
    if (lane == 0)  left1  = lx;

    // Wave-edge halos: global load, zero at row boundaries.
    if (lane == 0)  left0  = (i4_0 == 0)      ? 0.0f : x[(long)idx0 * 4 - 1];
    if (lane == 63) right1 = (i4_1 == L4 - 1) ? 0.0f : x[(long)idx1 * 4 + 4];

    float4 o0, o1;
    o0.x = fmaf(w0, left0, fmaf(w1, v0.x, fmaf(w2, v0.y, bc)));
    o0.y = fmaf(w0, v0.x,  fmaf(w1, v0.y, fmaf(w2, v0.z, bc)));
    o0.z = fmaf(w0, v0.y,  fmaf(w1, v0.z, fmaf(w2, v0.w, bc)));
    o0.w = fmaf(w0, v0.z,  fmaf(w1, v0.w, fmaf(w2, right0, bc)));

    o1.x = fmaf(w0, left1, fmaf(w1, v1.x, fmaf(w2, v1.y, bc)));
    o1.y = fmaf(w0, v1.x,  fmaf(w1, v1.y, fmaf(w2, v1.z, bc)));
    o1.z = fmaf(w0, v1.y,  fmaf(w1, v1.z, fmaf(w2, v1.w, bc)));
    o1.w = fmaf(w0, v1.z,  fmaf(w1, v1.w, fmaf(w2, right1, bc)));

    out4[idx0] = o0;
    out4[idx1] = o1;
}

extern "C" void kernel_launch(void* const* d_in, const int* in_sizes, int n_in,
                              void* d_out, int out_size, void* d_ws, size_t ws_size,
                              hipStream_t stream)
{
    const float* x    = (const float*)d_in[0];  // [B,C,L]
    const float* w    = (const float*)d_in[1];  // [C,3]
    const float* bias = (const float*)d_in[2];  // [C]
    float* out        = (float*)d_out;

    const int block = 256;
    const int grid  = NTHREADS / block;         // 16384, exact

    dwconv1d_kernel<<<grid, block, 0, stream>>>(
        (const float4*)x, x, w, bias, (float4*)out);
}